// Round 1
// baseline (180.043 us; speedup 1.0000x reference)
//
#include <hip/hip_runtime.h>

typedef __attribute__((ext_vector_type(4))) int   v4i;
typedef __attribute__((ext_vector_type(8))) short s8;     // 8 bf16
typedef __attribute__((ext_vector_type(4))) float f32x4;

__device__ __forceinline__ unsigned short f2bf(float f) {
  unsigned u = __builtin_bit_cast(unsigned, f);
  return (unsigned short)((u + 0x7fffu + ((u >> 16) & 1u)) >> 16);   // RNE
}

// ---- prep 1: weight [256][128][3][3] f32 -> ws_w [tap=9][co=256][ci=128] bf16
__global__ void wprep(const float* __restrict__ w, unsigned short* __restrict__ ww) {
  int o = blockIdx.x * 256 + threadIdx.x;            // 0..294911 exact
  int ci = o & 127, co = (o >> 7) & 255, tap = o >> 15;
  ww[o] = f2bf(w[(co * 128 + ci) * 9 + tap]);
}

// ---- prep 2: x [32][128][64][64] f32 -> ws_x NHWC bf16 [32][64][64][128]
__global__ void xprep(const float* __restrict__ x, unsigned int* __restrict__ xw) {
  __shared__ float tile[128][65];                    // +1 pad: conflict-free both phases
  int bid = blockIdx.x;                              // b*64 + h
  int b = bid >> 6, h = bid & 63;
  int t = threadIdx.x;
  {
    int wcol = t & 63, cl = t >> 6;
    const float* src = x + ((size_t)(b * 128) * 64 + h) * 64 + wcol;
#pragma unroll
    for (int j = 0; j < 32; ++j) {                   // coalesced 256B reads
      int ci = j * 4 + cl;
      tile[ci][wcol] = src[(size_t)ci * 4096];
    }
  }
  __syncthreads();
  {
    int ci2 = (t & 63) * 2, wl = t >> 6;
    unsigned int* dst = xw + (size_t)bid * 4096;     // dword units: 64 dwords per w
#pragma unroll
    for (int j = 0; j < 16; ++j) {                   // coalesced 256B packed writes
      int wcol = j * 4 + wl;
      unsigned p = (unsigned)f2bf(tile[ci2][wcol]) |
                   ((unsigned)f2bf(tile[ci2 + 1][wcol]) << 16);
      dst[wcol * 64 + (t & 63)] = p;
    }
  }
}

// ---- main: implicit GEMM, tile = 256 co x 128 pix (2 rows x 64 w), 8 waves
__global__ __launch_bounds__(512) void conv_mfma(
    const unsigned short* __restrict__ xw, const unsigned short* __restrict__ ww,
    const float* __restrict__ bias, float* __restrict__ out) {
  __shared__ unsigned short Xl[4 * 66 * 32];         // 16,896 B: [row][col][ci32]
  const int tid = threadIdx.x;
  const int lane = tid & 63;
  const int wv = tid >> 6;                           // 0..7
  const int mw = wv >> 1;                            // 0..3 : co base /64
  const int nw = wv & 1;                             // 0..1 : pixel base /64
  const int l15 = lane & 15, lg = lane >> 4;
  const int bid = blockIdx.x;
  const int b = bid >> 5, h0 = (bid & 31) << 1;

  f32x4 acc[4][4];
#pragma unroll
  for (int m = 0; m < 4; ++m)
#pragma unroll
    for (int n = 0; n < 4; ++n) acc[m][n] = (f32x4){0.f, 0.f, 0.f, 0.f};

  // B-fragment LDS byte base per n-frag (tap adds (kh*66+kw)*64 bytes)
  int bbase[4];
#pragma unroll
  for (int n = 0; n < 4; ++n) {
    int pix = nw * 64 + n * 16 + l15;
    int pr = pix >> 6, wc = pix & 63;
    bbase[n] = ((pr * 66 + wc) * 32 + lg * 8) * 2;
  }
  // A-fragment element base (adds m*2048 + tap*32768 + ci0)
  const int abase = (mw * 64 + l15) * 128 + lg * 8;

  for (int ci0 = 0; ci0 < 128; ci0 += 32) {
    // ---- stage Xlds[4][66][32] from NHWC bf16; 1056 16B slots, linear in LDS
#pragma unroll
    for (int it = 0; it < 3; ++it) {
      int s = tid + it * 512;
      if (s < 1056) {
        int g = s & 3, q = s >> 2;
        int cc = q % 66, rr = q / 66;
        int hh = h0 - 1 + rr, wg = cc - 1;
        v4i d = (v4i){0, 0, 0, 0};
        if ((unsigned)hh < 64u && (unsigned)wg < 64u)
          d = *(const v4i*)(xw + ((size_t)((b * 64 + hh) * 64 + wg) * 128 + ci0 + g * 8));
        *(v4i*)(&Xl[s * 8]) = d;
      }
    }
    __syncthreads();

#pragma unroll
    for (int kh = 0; kh < 3; ++kh)
#pragma unroll
      for (int kw = 0; kw < 3; ++kw) {
        const int tap = kh * 3 + kw;
        s8 a[4];
#pragma unroll
        for (int m = 0; m < 4; ++m)                  // A from L2-resident ws_w
          a[m] = *(const s8*)(ww + (tap * 32768 + m * 2048 + abase + ci0));
#pragma unroll
        for (int n = 0; n < 4; ++n) {
          s8 bf = *(const s8*)((const char*)Xl + (bbase[n] + (kh * 66 + kw) * 64));
#pragma unroll
          for (int m = 0; m < 4; ++m)
            acc[m][n] = __builtin_amdgcn_mfma_f32_16x16x32_bf16(a[m], bf, acc[m][n], 0, 0, 0);
        }
      }
    __syncthreads();
  }

  // ---- epilogue: + bias, store
#pragma unroll
  for (int m = 0; m < 4; ++m) {
    const int cob = mw * 64 + m * 16 + lg * 4;
    const f32x4 bi = *(const f32x4*)(bias + cob);
#pragma unroll
    for (int n = 0; n < 4; ++n) {
      int pix = nw * 64 + n * 16 + l15;
      int pr = pix >> 6, wc = pix & 63;
      size_t base = ((size_t)(b * 256 + cob) * 64 + (h0 + pr)) * 64 + wc;
#pragma unroll
      for (int r = 0; r < 4; ++r)
        out[base + (size_t)r * 4096] = acc[m][n][r] + bi[r];
    }
  }
}

// ---- fallback (ws too small): naive f32 conv, correct but slow
__global__ void conv_naive(const float* __restrict__ x, const float* __restrict__ w,
                           const float* __restrict__ bias, float* __restrict__ out) {
  int i = blockIdx.x * 256 + threadIdx.x;            // 33,554,432 exact
  int wc = i & 63, h = (i >> 6) & 63, co = (i >> 12) & 255, b = i >> 20;
  float s = bias[co];
  for (int ci = 0; ci < 128; ++ci)
#pragma unroll
    for (int kh = 0; kh < 3; ++kh) {
      int hh = h + kh - 1;
      if ((unsigned)hh >= 64u) continue;
#pragma unroll
      for (int kw = 0; kw < 3; ++kw) {
        int wg = wc + kw - 1;
        if ((unsigned)wg >= 64u) continue;
        s += x[((b * 128 + ci) * 64 + hh) * 64 + wg] *
             w[((co * 128 + ci) * 3 + kh) * 3 + kw];
      }
    }
  out[i] = s;
}

extern "C" void kernel_launch(void* const* d_in, const int* in_sizes, int n_in,
                              void* d_out, int out_size, void* d_ws, size_t ws_size,
                              hipStream_t stream) {
  const float* x    = (const float*)d_in[0];
  const float* w    = (const float*)d_in[1];
  const float* bias = (const float*)d_in[2];
  float* out = (float*)d_out;

  const size_t X_OFF = 1ull << 20;                               // ws_w in first 1 MB
  const size_t NEED  = X_OFF + 32ull * 64 * 64 * 128 * 2;        // + 33.5 MB NHWC bf16

  if (ws_size >= NEED) {
    unsigned short* ww = (unsigned short*)d_ws;
    unsigned short* xq = (unsigned short*)((char*)d_ws + X_OFF);
    hipLaunchKernelGGL(wprep, dim3(1152), dim3(256), 0, stream, w, ww);
    hipLaunchKernelGGL(xprep, dim3(2048), dim3(256), 0, stream, x, (unsigned int*)xq);
    hipLaunchKernelGGL(conv_mfma, dim3(1024), dim3(512), 0, stream, xq, ww, bias, out);
  } else {
    hipLaunchKernelGGL(conv_naive, dim3(131072), dim3(256), 0, stream, x, w, bias, out);
  }
}